// Round 3
// baseline (1244.777 us; speedup 1.0000x reference)
//
#include <hip/hip_runtime.h>
#include <stdint.h>

#define TT 16384   // tokens = B*S
#define DD 1024
#define EE 8
#define HH 2048

typedef __attribute__((ext_vector_type(8))) short bf16x8;
typedef __attribute__((ext_vector_type(4))) float f32x4;

__device__ __forceinline__ ushort f2bf(float f) {
  union { float f; unsigned u; } v; v.f = f;
  unsigned r = v.u + 0x7fffu + ((v.u >> 16) & 1u);
  return (ushort)(r >> 16);
}
__device__ __forceinline__ float bf2f(ushort u) {
  union { unsigned u; float f; } v; v.u = ((unsigned)u) << 16;
  return v.f;
}
__device__ __forceinline__ void g2l16(const void* g, void* l) {
  __builtin_amdgcn_global_load_lds((const __attribute__((address_space(1))) void*)g,
                                   (__attribute__((address_space(3))) void*)l, 16, 0, 0);
}

// ---------------- diagnostic sentinel ----------------
__global__ __launch_bounds__(256) void diag_k(float* __restrict__ out, float val) {
  out[(size_t)blockIdx.x * 256 + threadIdx.x] = val;
}

// ---------------- conversion kernels ----------------
__global__ __launch_bounds__(256) void cvt_x_k(const float4* __restrict__ x,
                                               ushort4* __restrict__ o) {
  int i = blockIdx.x * 256 + threadIdx.x;     // exactly TT*DD/4 threads
  float4 v = x[i];
  ushort4 r;
  r.x = f2bf(v.x); r.y = f2bf(v.y); r.z = f2bf(v.z); r.w = f2bf(v.w);
  o[i] = r;
}

// dst[e][c][r] = bf16(src[e][r][c]);  grid (C/32, R/32, E), block (32,8)
__global__ __launch_bounds__(256) void cvt_t_k(const float* __restrict__ src,
                                               ushort* __restrict__ dst, int R, int C) {
  __shared__ float tile[32][33];
  int e = blockIdx.z;
  int c0 = blockIdx.x * 32, r0 = blockIdx.y * 32;
  const float* s = src + (size_t)e * R * C;
  ushort* d = dst + (size_t)e * R * C;
  int tx = threadIdx.x;
  #pragma unroll
  for (int i = threadIdx.y; i < 32; i += 8)
    tile[i][tx] = s[(size_t)(r0 + i) * C + c0 + tx];
  __syncthreads();
  #pragma unroll
  for (int i = threadIdx.y; i < 32; i += 8)
    d[(size_t)(c0 + i) * R + r0 + tx] = f2bf(tile[tx][i]);
}

// ---------------- gating ----------------
__global__ __launch_bounds__(256) void gate_k(const float* __restrict__ x,
                                              const float* __restrict__ Wg,
                                              const float* __restrict__ bg,
                                              float* __restrict__ wk,
                                              int* __restrict__ idx,
                                              int* __restrict__ cnt) {
  int t = blockIdx.x * 4 + (threadIdx.x >> 6);
  int lane = threadIdx.x & 63;
  const float* xr = x + (size_t)t * DD;
  // fp64 accumulation -> ranking matches true values (top-2 flip guard)
  double acc[8] = {0, 0, 0, 0, 0, 0, 0, 0};
  for (int d = lane; d < DD; d += 64) {
    float xv = xr[d];
    const float4 wa = *(const float4*)(Wg + d * 8);
    const float4 wb = *(const float4*)(Wg + d * 8 + 4);
    acc[0] += (double)xv * wa.x; acc[1] += (double)xv * wa.y;
    acc[2] += (double)xv * wa.z; acc[3] += (double)xv * wa.w;
    acc[4] += (double)xv * wb.x; acc[5] += (double)xv * wb.y;
    acc[6] += (double)xv * wb.z; acc[7] += (double)xv * wb.w;
  }
  #pragma unroll
  for (int q = 0; q < 8; q++)
    #pragma unroll
    for (int s = 1; s < 64; s <<= 1) acc[q] += __shfl_xor(acc[q], s, 64);
  if (lane == 0) {
    double lg[8];
    #pragma unroll
    for (int q = 0; q < 8; q++) lg[q] = acc[q] + (double)bg[q];
    int i0 = 0;
    #pragma unroll
    for (int q = 1; q < 8; q++) if (lg[q] > lg[i0]) i0 = q;
    int i1 = (i0 == 0) ? 1 : 0;
    #pragma unroll
    for (int q = 0; q < 8; q++) if (q != i0 && lg[q] > lg[i1]) i1 = q;
    double m = fmax(lg[i0], lg[i1]);
    double p0 = exp(lg[i0] - m), p1 = exp(lg[i1] - m);
    double s = p0 + p1;
    wk[t * 2 + 0] = (float)(p0 / s);
    wk[t * 2 + 1] = (float)(p1 / s);
    idx[t * 2 + 0] = i0;
    idx[t * 2 + 1] = i1;
    atomicAdd(&cnt[i0], 1);
    atomicAdd(&cnt[i1], 1);
  }
}

__global__ void prefix_k(const int* __restrict__ cnt, int* __restrict__ eoff,
                         int* __restrict__ cur) {
  if (threadIdx.x == 0) {
    int s = 0;
    for (int e = 0; e < EE; e++) { eoff[e] = s; cur[e] = s; s += cnt[e]; }
    eoff[EE] = s;   // == 2*TT
  }
}

__global__ __launch_bounds__(256) void scatter_k(const int* __restrict__ idx,
                                                 int* __restrict__ cur,
                                                 int* __restrict__ rowsb) {
  int t = blockIdx.x * 256 + threadIdx.x;
  int lane = threadIdx.x & 63;
  unsigned long long lt = (lane == 63) ? 0x7fffffffffffffffull
                                       : ((1ull << lane) - 1ull);
  #pragma unroll
  for (int k = 0; k < 2; k++) {
    int e = idx[t * 2 + k];
    int pos = 0;
    #pragma unroll
    for (int ex = 0; ex < EE; ex++) {
      unsigned long long m = __ballot(e == ex);
      if (e == ex) {
        int leader = __ffsll((unsigned long long)m) - 1;
        int base = 0;
        if (lane == leader) base = atomicAdd(&cur[ex], __popcll(m));
        base = __shfl(base, leader, 64);
        pos = base + __popcll(m & lt);
      }
    }
    rowsb[pos] = t * 2 + k;
  }
}

// ---------------- routed GEMM (m97 structure), windowed over routed rows ----
// Tiles are 128-row chunks of an expert's routed-row segment; a tile belongs
// to the window [w0,w1) containing its FIRST row. hbuf holds rows [w0, w1+128).
// MODE 0: A = xbf gathered via rowsb, Out = hbuf[(r-w0)] = relu(A@W1t^T + b1)
// MODE 1: A = hbuf[(r-w0)],           Out[slot]          = A@W2t^T + b2
template <int MODE>
__global__ __launch_bounds__(256) void ffn_gemm(const ushort* __restrict__ A,
                                                const ushort* __restrict__ Bt,
                                                const float* __restrict__ bias,
                                                ushort* __restrict__ Out,
                                                const int* __restrict__ rowsb,
                                                const int* __restrict__ eoff,
                                                int K, int N, int w0, int w1) {
  const int e = blockIdx.z;
  const int n0 = blockIdx.x * 128;
  const int e0 = eoff[e];
  const int rows_e = eoff[e + 1] - e0;
  const int j0 = (e0 >= w0) ? 0 : ((w0 - e0 + 127) >> 7);
  const int m0 = (j0 + blockIdx.y) << 7;
  const int fr = e0 + m0;                    // first routed row of this tile
  if (m0 >= rows_e || fr >= w1) return;

  __shared__ __align__(16) ushort As[128 * 32];
  __shared__ __align__(16) ushort Bs[128 * 32];

  const int tid = threadIdx.x;
  const int wave = tid >> 6, lane = tid & 63;
  const int ln15 = lane & 15, kq = lane >> 4;
  const int wr = wave >> 1, wc = wave & 1;

  // staging: LDS byte o = row*64 + kbyte; 256 threads x 16B x 2 issues = 8KiB
  const int o0 = wave * 2048 + lane * 16;
  const int o1 = o0 + 1024;
  const int rA0 = o0 >> 6, kc0 = (o0 >> 4) & 3;
  const int rA1 = o1 >> 6, kc1 = (o1 >> 4) & 3;

  size_t aoff0, aoff1;
  {
    const int r0 = min(fr + rA0, 2 * TT - 1);
    const int r1 = min(fr + rA1, 2 * TT - 1);
    if (MODE == 0) {
      aoff0 = (size_t)(rowsb[r0] >> 1) * K + kc0 * 8;
      aoff1 = (size_t)(rowsb[r1] >> 1) * K + kc1 * 8;
    } else {
      aoff0 = (size_t)(r0 - w0) * K + kc0 * 8;
      aoff1 = (size_t)(r1 - w0) * K + kc1 * 8;
    }
  }
  const size_t boff0 = ((size_t)e * N + n0 + rA0) * K + kc0 * 8;
  const size_t boff1 = ((size_t)e * N + n0 + rA1) * K + kc1 * 8;

  ushort* lA0 = As + wave * 1024;
  ushort* lA1 = As + wave * 1024 + 512;
  ushort* lB0 = Bs + wave * 1024;
  ushort* lB1 = Bs + wave * 1024 + 512;

  f32x4 acc[4][4];
  #pragma unroll
  for (int m = 0; m < 4; m++)
    #pragma unroll
    for (int n = 0; n < 4; n++) acc[m][n] = (f32x4){0.f, 0.f, 0.f, 0.f};

  for (int k0 = 0; k0 < K; k0 += 32) {
    g2l16(A + aoff0 + k0, lA0);
    g2l16(A + aoff1 + k0, lA1);
    g2l16(Bt + boff0 + k0, lB0);
    g2l16(Bt + boff1 + k0, lB1);
    __syncthreads();

    bf16x8 a[4], b[4];
    #pragma unroll
    for (int m = 0; m < 4; m++)
      a[m] = *(const bf16x8*)(As + (wr * 64 + m * 16 + ln15) * 32 + kq * 8);
    #pragma unroll
    for (int n = 0; n < 4; n++)
      b[n] = *(const bf16x8*)(Bs + (wc * 64 + n * 16 + ln15) * 32 + kq * 8);
    #pragma unroll
    for (int m = 0; m < 4; m++)
      #pragma unroll
      for (int n = 0; n < 4; n++)
        acc[m][n] = __builtin_amdgcn_mfma_f32_16x16x32_bf16(a[m], b[n], acc[m][n], 0, 0, 0);
    __syncthreads();
  }

  // epilogue: C col = ln15, row = kq*4 + j (m89-verified layout)
  #pragma unroll
  for (int n = 0; n < 4; n++) {
    const int col = n0 + wc * 64 + n * 16 + ln15;
    const float bv = bias[(size_t)e * N + col];
    #pragma unroll
    for (int m = 0; m < 4; m++) {
      #pragma unroll
      for (int j = 0; j < 4; j++) {
        const int rloc = wr * 64 + m * 16 + kq * 4 + j;
        if (rloc < rows_e - m0) {
          float v = acc[m][n][j] + bv;
          const int r = fr + rloc;
          if (MODE == 0) {
            v = fmaxf(v, 0.0f);
            Out[(size_t)(r - w0) * N + col] = f2bf(v);
          } else {
            const int slot = rowsb[r];           // token*2 + k
            Out[(size_t)slot * N + col] = f2bf(v);
          }
        }
      }
    }
  }
}

// ---------------- in-place combine (d_out: bf16 slot rows -> fp32 rows) ----
// Block t owns out bytes [t*4096, t*4096+4096): reads bf16 rows 2t,2t+1 from
// that exact range into regs, barriers (vmcnt drained), rewrites as fp32.
__global__ __launch_bounds__(256) void combine_k(float* __restrict__ out,
                                                 const float* __restrict__ wk) {
  const int t = blockIdx.x;
  const int dq = threadIdx.x;
  const ushort4* u4 = (const ushort4*)out;
  ushort4 a = u4[(size_t)t * 512 + dq];
  ushort4 b = u4[(size_t)t * 512 + 256 + dq];
  float w0 = wk[t * 2], w1 = wk[t * 2 + 1];
  float4 r;
  r.x = w0 * bf2f(a.x) + w1 * bf2f(b.x);
  r.y = w0 * bf2f(a.y) + w1 * bf2f(b.y);
  r.z = w0 * bf2f(a.z) + w1 * bf2f(b.z);
  r.w = w0 * bf2f(a.w) + w1 * bf2f(b.w);
  __syncthreads();   // all block reads complete before any write
  ((float4*)out)[(size_t)t * 256 + dq] = r;
}

// ---------------- launch ----------------
extern "C" void kernel_launch(void* const* d_in, const int* in_sizes, int n_in,
                              void* d_out, int out_size, void* d_ws, size_t ws_size,
                              hipStream_t stream) {
  const float* x  = (const float*)d_in[0];
  const float* Wg = (const float*)d_in[1];
  const float* bg = (const float*)d_in[2];
  const float* W1 = (const float*)d_in[3];
  const float* b1 = (const float*)d_in[4];
  const float* W2 = (const float*)d_in[5];
  const float* b2 = (const float*)d_in[6];

  // ---- workspace carve-up: control first, then bf16 buffers, then hbuf ----
  char* ws = (char*)d_ws;
  float* wk    = (float*)ws;                  // 2*TT
  int*   idx   = (int*)(wk + 2 * TT);         // 2*TT
  int*   rowsb = idx + 2 * TT;                // 2*TT
  int*   cnt   = rowsb + 2 * TT;              // EE
  int*   eoff  = cnt + EE;                    // EE+1
  int*   cur   = eoff + EE + 1;               // EE
  size_t ctl_end = (((size_t)((char*)(cur + EE) - ws)) + 255) & ~(size_t)255;
  ushort* xbf = (ushort*)(ws + ctl_end);      // TT*DD        (32 MiB)
  ushort* w1t = xbf + (size_t)TT * DD;        // EE*HH*DD     (32 MiB)
  ushort* w2t = w1t + (size_t)EE * HH * DD;   // EE*DD*HH     (32 MiB)
  char*   hb  = (char*)(w2t + (size_t)EE * DD * HH);
  const size_t fixed = (size_t)(hb - ws);

  // adaptive hbuf window size (rows, multiple of 128, +128 straddle slack)
  long long rows_avail = (ws_size > fixed)
      ? (long long)((ws_size - fixed) / ((size_t)HH * 2)) : 0;
  int usable;
  if (rows_avail >= 2 * TT) usable = 2 * TT;
  else usable = (int)(((rows_avail - 128) / 128) * 128);

  if (usable < 1024) {
    // cannot fit: encode ws_size (MiB) into the output as a diagnostic
    float val = 100.0f + (float)(ws_size >> 20);
    diag_k<<<TT * DD / 256, 256, 0, stream>>>((float*)d_out, val);
    return;
  }
  ushort* hbuf  = (ushort*)hb;
  ushort* yslot = (ushort*)d_out;   // 2*TT x DD bf16 == TT x DD fp32 bytes

  hipMemsetAsync(cnt, 0, EE * sizeof(int), stream);

  cvt_x_k<<<TT * DD / 4 / 256, 256, 0, stream>>>((const float4*)x, (ushort4*)xbf);
  // W1 [E][D][H] -> w1t [E][H][D]
  cvt_t_k<<<dim3(HH / 32, DD / 32, EE), dim3(32, 8), 0, stream>>>(W1, w1t, DD, HH);
  // W2 [E][H][D] -> w2t [E][D][H]
  cvt_t_k<<<dim3(DD / 32, HH / 32, EE), dim3(32, 8), 0, stream>>>(W2, w2t, HH, DD);

  gate_k<<<TT / 4, 256, 0, stream>>>(x, Wg, bg, wk, idx, cnt);
  prefix_k<<<1, 64, 0, stream>>>(cnt, eoff, cur);
  scatter_k<<<TT / 256, 256, 0, stream>>>(idx, cur, rowsb);

  const int maxtiles = usable / 128 + 1;
  for (int win0 = 0; win0 < 2 * TT; win0 += usable) {
    int win1 = min(win0 + usable, 2 * TT);
    ffn_gemm<0><<<dim3(HH / 128, maxtiles, EE), 256, 0, stream>>>(
        xbf, w1t, b1, hbuf, rowsb, eoff, DD, HH, win0, win1);
    ffn_gemm<1><<<dim3(DD / 128, maxtiles, EE), 256, 0, stream>>>(
        hbuf, w2t, b2, yslot, rowsb, eoff, HH, DD, win0, win1);
  }

  combine_k<<<TT, 256, 0, stream>>>((float*)d_out, wk);
}

// Round 6
// 891.672 us; speedup vs baseline: 1.3960x; 1.3960x over previous
//
#include <hip/hip_runtime.h>
#include <stdint.h>

#define TT 16384   // tokens = B*S
#define DD 1024
#define EE 8
#define HH 2048

typedef __attribute__((ext_vector_type(8))) short bf16x8;
typedef __attribute__((ext_vector_type(4))) float f32x4;

__device__ __forceinline__ ushort f2bf(float f) {
  union { float f; unsigned u; } v; v.f = f;
  unsigned r = v.u + 0x7fffu + ((v.u >> 16) & 1u);
  return (ushort)(r >> 16);
}
__device__ __forceinline__ float bf2f(ushort u) {
  union { unsigned u; float f; } v; v.u = ((unsigned)u) << 16;
  return v.f;
}
__device__ __forceinline__ void g2l16(const void* g, void* l) {
  __builtin_amdgcn_global_load_lds((const __attribute__((address_space(1))) void*)g,
                                   (__attribute__((address_space(3))) void*)l, 16, 0, 0);
}

// ---------------- diagnostic sentinel ----------------
__global__ __launch_bounds__(256) void diag_k(float* __restrict__ out, float val) {
  out[(size_t)blockIdx.x * 256 + threadIdx.x] = val;
}

// ---------------- conversion kernels ----------------
__global__ __launch_bounds__(256) void cvt_x_k(const float4* __restrict__ x,
                                               ushort4* __restrict__ o) {
  int i = blockIdx.x * 256 + threadIdx.x;     // exactly TT*DD/4 threads
  float4 v = x[i];
  ushort4 r;
  r.x = f2bf(v.x); r.y = f2bf(v.y); r.z = f2bf(v.z); r.w = f2bf(v.w);
  o[i] = r;
}

// dst[e][c][r] = bf16(src[e][r][c]);  grid (C/32, R/32, E), block (32,8)
__global__ __launch_bounds__(256) void cvt_t_k(const float* __restrict__ src,
                                               ushort* __restrict__ dst, int R, int C) {
  __shared__ float tile[32][33];
  int e = blockIdx.z;
  int c0 = blockIdx.x * 32, r0 = blockIdx.y * 32;
  const float* s = src + (size_t)e * R * C;
  ushort* d = dst + (size_t)e * R * C;
  int tx = threadIdx.x;
  #pragma unroll
  for (int i = threadIdx.y; i < 32; i += 8)
    tile[i][tx] = s[(size_t)(r0 + i) * C + c0 + tx];
  __syncthreads();
  #pragma unroll
  for (int i = threadIdx.y; i < 32; i += 8)
    d[(size_t)(c0 + i) * R + r0 + tx] = f2bf(tile[tx][i]);
}

// ---------------- gating (NO global atomics — see hist_k) ----------------
__global__ __launch_bounds__(256) void gate_k(const float* __restrict__ x,
                                              const float* __restrict__ Wg,
                                              const float* __restrict__ bg,
                                              float* __restrict__ wk,
                                              int* __restrict__ idx) {
  int t = blockIdx.x * 4 + (threadIdx.x >> 6);
  int lane = threadIdx.x & 63;
  const float* xr = x + (size_t)t * DD;
  // fp64 accumulation -> ranking matches true values (top-2 flip guard)
  double acc[8] = {0, 0, 0, 0, 0, 0, 0, 0};
  for (int d = lane; d < DD; d += 64) {
    float xv = xr[d];
    const float4 wa = *(const float4*)(Wg + d * 8);
    const float4 wb = *(const float4*)(Wg + d * 8 + 4);
    acc[0] += (double)xv * wa.x; acc[1] += (double)xv * wa.y;
    acc[2] += (double)xv * wa.z; acc[3] += (double)xv * wa.w;
    acc[4] += (double)xv * wb.x; acc[5] += (double)xv * wb.y;
    acc[6] += (double)xv * wb.z; acc[7] += (double)xv * wb.w;
  }
  #pragma unroll
  for (int q = 0; q < 8; q++)
    #pragma unroll
    for (int s = 1; s < 64; s <<= 1) acc[q] += __shfl_xor(acc[q], s, 64);
  if (lane == 0) {
    double lg[8];
    #pragma unroll
    for (int q = 0; q < 8; q++) lg[q] = acc[q] + (double)bg[q];
    int i0 = 0;
    #pragma unroll
    for (int q = 1; q < 8; q++) if (lg[q] > lg[i0]) i0 = q;
    int i1 = (i0 == 0) ? 1 : 0;
    #pragma unroll
    for (int q = 0; q < 8; q++) if (q != i0 && lg[q] > lg[i1]) i1 = q;
    double m = fmax(lg[i0], lg[i1]);
    double p0 = exp(lg[i0] - m), p1 = exp(lg[i1] - m);
    double s = p0 + p1;
    wk[t * 2 + 0] = (float)(p0 / s);
    wk[t * 2 + 1] = (float)(p1 / s);
    idx[t * 2 + 0] = i0;
    idx[t * 2 + 1] = i1;
  }
}

// LDS-aggregated expert histogram: 64 blocks -> 8 global atomics each (512
// total, vs 32768 same-cacheline atomics that cost 393us in round 3).
__global__ __launch_bounds__(256) void hist_k(const int* __restrict__ idx,
                                              int* __restrict__ cnt) {
  __shared__ int h[EE];
  if (threadIdx.x < EE) h[threadIdx.x] = 0;
  __syncthreads();
  int i = blockIdx.x * 256 + threadIdx.x;          // gridDim.x*256 == TT
  atomicAdd(&h[idx[i * 2 + 0]], 1);
  atomicAdd(&h[idx[i * 2 + 1]], 1);
  __syncthreads();
  if (threadIdx.x < EE) atomicAdd(&cnt[threadIdx.x], h[threadIdx.x]);
}

__global__ void prefix_k(const int* __restrict__ cnt, int* __restrict__ eoff,
                         int* __restrict__ cur) {
  if (threadIdx.x == 0) {
    int s = 0;
    for (int e = 0; e < EE; e++) { eoff[e] = s; cur[e] = s; s += cnt[e]; }
    eoff[EE] = s;   // == 2*TT
  }
}

__global__ __launch_bounds__(256) void scatter_k(const int* __restrict__ idx,
                                                 int* __restrict__ cur,
                                                 int* __restrict__ rowsb) {
  int t = blockIdx.x * 256 + threadIdx.x;
  int lane = threadIdx.x & 63;
  unsigned long long lt = (lane == 63) ? 0x7fffffffffffffffull
                                       : ((1ull << lane) - 1ull);
  #pragma unroll
  for (int k = 0; k < 2; k++) {
    int e = idx[t * 2 + k];
    int pos = 0;
    #pragma unroll
    for (int ex = 0; ex < EE; ex++) {
      unsigned long long m = __ballot(e == ex);
      if (e == ex) {
        int leader = __ffsll((unsigned long long)m) - 1;
        int base = 0;
        if (lane == leader) base = atomicAdd(&cur[ex], __popcll(m));
        base = __shfl(base, leader, 64);
        pos = base + __popcll(m & lt);
      }
    }
    rowsb[pos] = t * 2 + k;
  }
}

// ---------------- routed GEMM (m97 structure), windowed over routed rows ----
// MODE 0: A = xbf gathered via rowsb, Out = hbuf[(r-w0)] = relu(A@W1t^T + b1)
// MODE 1: A = hbuf[(r-w0)],           Out[slot]          = A@W2t^T + b2
template <int MODE>
__global__ __launch_bounds__(256) void ffn_gemm(const ushort* __restrict__ A,
                                                const ushort* __restrict__ Bt,
                                                const float* __restrict__ bias,
                                                ushort* __restrict__ Out,
                                                const int* __restrict__ rowsb,
                                                const int* __restrict__ eoff,
                                                int K, int N, int w0, int w1) {
  const int e = blockIdx.z;
  const int n0 = blockIdx.x * 128;
  const int e0 = eoff[e];
  const int rows_e = eoff[e + 1] - e0;
  const int j0 = (e0 >= w0) ? 0 : ((w0 - e0 + 127) >> 7);
  const int m0 = (j0 + blockIdx.y) << 7;
  const int fr = e0 + m0;                    // first routed row of this tile
  if (m0 >= rows_e || fr >= w1) return;

  __shared__ __align__(16) ushort As[128 * 32];
  __shared__ __align__(16) ushort Bs[128 * 32];

  const int tid = threadIdx.x;
  const int wave = tid >> 6, lane = tid & 63;
  const int ln15 = lane & 15, kq = lane >> 4;
  const int wr = wave >> 1, wc = wave & 1;

  // staging: LDS byte o = row*64 + kbyte; 256 threads x 16B x 2 issues = 8KiB
  const int o0 = wave * 2048 + lane * 16;
  const int o1 = o0 + 1024;
  const int rA0 = o0 >> 6, kc0 = (o0 >> 4) & 3;
  const int rA1 = o1 >> 6, kc1 = (o1 >> 4) & 3;

  size_t aoff0, aoff1;
  {
    const int r0 = min(fr + rA0, 2 * TT - 1);
    const int r1 = min(fr + rA1, 2 * TT - 1);
    if (MODE == 0) {
      aoff0 = (size_t)(rowsb[r0] >> 1) * K + kc0 * 8;
      aoff1 = (size_t)(rowsb[r1] >> 1) * K + kc1 * 8;
    } else {
      aoff0 = (size_t)(r0 - w0) * K + kc0 * 8;
      aoff1 = (size_t)(r1 - w0) * K + kc1 * 8;
    }
  }
  const size_t boff0 = ((size_t)e * N + n0 + rA0) * K + kc0 * 8;
  const size_t boff1 = ((size_t)e * N + n0 + rA1) * K + kc1 * 8;

  ushort* lA0 = As + wave * 1024;
  ushort* lA1 = As + wave * 1024 + 512;
  ushort* lB0 = Bs + wave * 1024;
  ushort* lB1 = Bs + wave * 1024 + 512;

  f32x4 acc[4][4];
  #pragma unroll
  for (int m = 0; m < 4; m++)
    #pragma unroll
    for (int n = 0; n < 4; n++) acc[m][n] = (f32x4){0.f, 0.f, 0.f, 0.f};

  for (int k0 = 0; k0 < K; k0 += 32) {
    g2l16(A + aoff0 + k0, lA0);
    g2l16(A + aoff1 + k0, lA1);
    g2l16(Bt + boff0 + k0, lB0);
    g2l16(Bt + boff1 + k0, lB1);
    __syncthreads();

    bf16x8 a[4], b[4];
    #pragma unroll
    for (int m = 0; m < 4; m++)
      a[m] = *(const bf16x8*)(As + (wr * 64 + m * 16 + ln15) * 32 + kq * 8);
    #pragma unroll
    for (int n = 0; n < 4; n++)
      b[n] = *(const bf16x8*)(Bs + (wc * 64 + n * 16 + ln15) * 32 + kq * 8);
    #pragma unroll
    for (int m = 0; m < 4; m++)
      #pragma unroll
      for (int n = 0; n < 4; n++)
        acc[m][n] = __builtin_amdgcn_mfma_f32_16x16x32_bf16(a[m], b[n], acc[m][n], 0, 0, 0);
    __syncthreads();
  }

  // epilogue: C col = ln15, row = kq*4 + j (m89-verified layout)
  #pragma unroll
  for (int n = 0; n < 4; n++) {
    const int col = n0 + wc * 64 + n * 16 + ln15;
    const float bv = bias[(size_t)e * N + col];
    #pragma unroll
    for (int m = 0; m < 4; m++) {
      #pragma unroll
      for (int j = 0; j < 4; j++) {
        const int rloc = wr * 64 + m * 16 + kq * 4 + j;
        if (rloc < rows_e - m0) {
          float v = acc[m][n][j] + bv;
          const int r = fr + rloc;
          if (MODE == 0) {
            v = fmaxf(v, 0.0f);
            Out[(size_t)(r - w0) * N + col] = f2bf(v);
          } else {
            const int slot = rowsb[r];           // token*2 + k
            Out[(size_t)slot * N + col] = f2bf(v);
          }
        }
      }
    }
  }
}

// ---------------- in-place combine (d_out: bf16 slot rows -> fp32 rows) ----
__global__ __launch_bounds__(256) void combine_k(float* __restrict__ out,
                                                 const float* __restrict__ wk) {
  const int t = blockIdx.x;
  const int dq = threadIdx.x;
  const ushort4* u4 = (const ushort4*)out;
  ushort4 a = u4[(size_t)t * 512 + dq];
  ushort4 b = u4[(size_t)t * 512 + 256 + dq];
  float w0 = wk[t * 2], w1 = wk[t * 2 + 1];
  float4 r;
  r.x = w0 * bf2f(a.x) + w1 * bf2f(b.x);
  r.y = w0 * bf2f(a.y) + w1 * bf2f(b.y);
  r.z = w0 * bf2f(a.z) + w1 * bf2f(b.z);
  r.w = w0 * bf2f(a.w) + w1 * bf2f(b.w);
  __syncthreads();   // all block reads complete before any write
  ((float4*)out)[(size_t)t * 256 + dq] = r;
}

// ---------------- launch ----------------
extern "C" void kernel_launch(void* const* d_in, const int* in_sizes, int n_in,
                              void* d_out, int out_size, void* d_ws, size_t ws_size,
                              hipStream_t stream) {
  const float* x  = (const float*)d_in[0];
  const float* Wg = (const float*)d_in[1];
  const float* bg = (const float*)d_in[2];
  const float* W1 = (const float*)d_in[3];
  const float* b1 = (const float*)d_in[4];
  const float* W2 = (const float*)d_in[5];
  const float* b2 = (const float*)d_in[6];

  // ---- workspace carve-up: control first, then bf16 buffers, then hbuf ----
  char* ws = (char*)d_ws;
  float* wk    = (float*)ws;                  // 2*TT
  int*   idx   = (int*)(wk + 2 * TT);         // 2*TT
  int*   rowsb = idx + 2 * TT;                // 2*TT
  int*   cnt   = rowsb + 2 * TT;              // EE
  int*   eoff  = cnt + EE;                    // EE+1
  int*   cur   = eoff + EE + 1;               // EE
  size_t ctl_end = (((size_t)((char*)(cur + EE) - ws)) + 255) & ~(size_t)255;
  ushort* xbf = (ushort*)(ws + ctl_end);      // TT*DD        (32 MiB)
  ushort* w1t = xbf + (size_t)TT * DD;        // EE*HH*DD     (32 MiB)
  ushort* w2t = w1t + (size_t)EE * HH * DD;   // EE*DD*HH     (32 MiB)
  char*   hb  = (char*)(w2t + (size_t)EE * DD * HH);
  const size_t fixed = (size_t)(hb - ws);

  // adaptive hbuf window size (rows, multiple of 128, +128 straddle slack)
  long long rows_avail = (ws_size > fixed)
      ? (long long)((ws_size - fixed) / ((size_t)HH * 2)) : 0;
  int usable;
  if (rows_avail >= 2 * TT) usable = 2 * TT;
  else usable = (int)(((rows_avail - 128) / 128) * 128);

  if (usable < 1024) {
    float val = 100.0f + (float)(ws_size >> 20);
    diag_k<<<TT * DD / 256, 256, 0, stream>>>((float*)d_out, val);
    return;
  }
  ushort* hbuf  = (ushort*)hb;
  ushort* yslot = (ushort*)d_out;   // 2*TT x DD bf16 == TT x DD fp32 bytes

  hipMemsetAsync(cnt, 0, EE * sizeof(int), stream);

  cvt_x_k<<<TT * DD / 4 / 256, 256, 0, stream>>>((const float4*)x, (ushort4*)xbf);
  // W1 [E][D][H] -> w1t [E][H][D]
  cvt_t_k<<<dim3(HH / 32, DD / 32, EE), dim3(32, 8), 0, stream>>>(W1, w1t, DD, HH);
  // W2 [E][H][D] -> w2t [E][D][H]
  cvt_t_k<<<dim3(DD / 32, HH / 32, EE), dim3(32, 8), 0, stream>>>(W2, w2t, HH, DD);

  gate_k<<<TT / 4, 256, 0, stream>>>(x, Wg, bg, wk, idx);
  hist_k<<<TT / 256, 256, 0, stream>>>(idx, cnt);
  prefix_k<<<1, 64, 0, stream>>>(cnt, eoff, cur);
  scatter_k<<<TT / 256, 256, 0, stream>>>(idx, cur, rowsb);

  const int maxtiles = usable / 128 + 1;
  for (int win0 = 0; win0 < 2 * TT; win0 += usable) {
    int win1 = min(win0 + usable, 2 * TT);
    ffn_gemm<0><<<dim3(HH / 128, maxtiles, EE), 256, 0, stream>>>(
        xbf, w1t, b1, hbuf, rowsb, eoff, DD, HH, win0, win1);
    ffn_gemm<1><<<dim3(DD / 128, maxtiles, EE), 256, 0, stream>>>(
        hbuf, w2t, b2, yslot, rowsb, eoff, HH, DD, win0, win1);
  }

  combine_k<<<TT, 256, 0, stream>>>((float*)d_out, wk);
}

// Round 10
// 730.463 us; speedup vs baseline: 1.7041x; 1.2207x over previous
//
#include <hip/hip_runtime.h>
#include <stdint.h>

#define TT 16384   // tokens = B*S
#define DD 1024
#define EE 8
#define HH 2048

typedef __attribute__((ext_vector_type(8))) short bf16x8;
typedef __attribute__((ext_vector_type(4))) float f32x4;

__device__ __forceinline__ ushort f2bf(float f) {
  union { float f; unsigned u; } v; v.f = f;
  unsigned r = v.u + 0x7fffu + ((v.u >> 16) & 1u);
  return (ushort)(r >> 16);
}
__device__ __forceinline__ float bf2f(ushort u) {
  union { unsigned u; float f; } v; v.u = ((unsigned)u) << 16;
  return v.f;
}
__device__ __forceinline__ void g2l16(const void* g, void* l) {
  __builtin_amdgcn_global_load_lds((const __attribute__((address_space(1))) void*)g,
                                   (__attribute__((address_space(3))) void*)l, 16, 0, 0);
}

// ---------------- diagnostic sentinel ----------------
__global__ __launch_bounds__(256) void diag_k(float* __restrict__ out, float val) {
  out[(size_t)blockIdx.x * 256 + threadIdx.x] = val;
}

// ---------------- conversion kernels ----------------
__global__ __launch_bounds__(256) void cvt_x_k(const float4* __restrict__ x,
                                               ushort4* __restrict__ o) {
  int i = blockIdx.x * 256 + threadIdx.x;     // exactly TT*DD/4 threads
  float4 v = x[i];
  ushort4 r;
  r.x = f2bf(v.x); r.y = f2bf(v.y); r.z = f2bf(v.z); r.w = f2bf(v.w);
  o[i] = r;
}

// dst[e][c][r] = bf16(src[e][r][c]);  grid (C/32, R/32, E), block (32,8)
__global__ __launch_bounds__(256) void cvt_t_k(const float* __restrict__ src,
                                               ushort* __restrict__ dst, int R, int C) {
  __shared__ float tile[32][33];
  int e = blockIdx.z;
  int c0 = blockIdx.x * 32, r0 = blockIdx.y * 32;
  const float* s = src + (size_t)e * R * C;
  ushort* d = dst + (size_t)e * R * C;
  int tx = threadIdx.x;
  #pragma unroll
  for (int i = threadIdx.y; i < 32; i += 8)
    tile[i][tx] = s[(size_t)(r0 + i) * C + c0 + tx];
  __syncthreads();
  #pragma unroll
  for (int i = threadIdx.y; i < 32; i += 8)
    d[(size_t)(c0 + i) * R + r0 + tx] = f2bf(tile[tx][i]);
}

// ---------------- gating (NO global atomics — see hist_k) ----------------
__global__ __launch_bounds__(256) void gate_k(const float* __restrict__ x,
                                              const float* __restrict__ Wg,
                                              const float* __restrict__ bg,
                                              float* __restrict__ wk,
                                              int* __restrict__ idx) {
  int t = blockIdx.x * 4 + (threadIdx.x >> 6);
  int lane = threadIdx.x & 63;
  const float* xr = x + (size_t)t * DD;
  // fp64 accumulation -> ranking matches true values (top-2 flip guard)
  double acc[8] = {0, 0, 0, 0, 0, 0, 0, 0};
  for (int d = lane; d < DD; d += 64) {
    float xv = xr[d];
    const float4 wa = *(const float4*)(Wg + d * 8);
    const float4 wb = *(const float4*)(Wg + d * 8 + 4);
    acc[0] += (double)xv * wa.x; acc[1] += (double)xv * wa.y;
    acc[2] += (double)xv * wa.z; acc[3] += (double)xv * wa.w;
    acc[4] += (double)xv * wb.x; acc[5] += (double)xv * wb.y;
    acc[6] += (double)xv * wb.z; acc[7] += (double)xv * wb.w;
  }
  #pragma unroll
  for (int q = 0; q < 8; q++)
    #pragma unroll
    for (int s = 1; s < 64; s <<= 1) acc[q] += __shfl_xor(acc[q], s, 64);
  if (lane == 0) {
    double lg[8];
    #pragma unroll
    for (int q = 0; q < 8; q++) lg[q] = acc[q] + (double)bg[q];
    int i0 = 0;
    #pragma unroll
    for (int q = 1; q < 8; q++) if (lg[q] > lg[i0]) i0 = q;
    int i1 = (i0 == 0) ? 1 : 0;
    #pragma unroll
    for (int q = 0; q < 8; q++) if (q != i0 && lg[q] > lg[i1]) i1 = q;
    double m = fmax(lg[i0], lg[i1]);
    double p0 = exp(lg[i0] - m), p1 = exp(lg[i1] - m);
    double s = p0 + p1;
    wk[t * 2 + 0] = (float)(p0 / s);
    wk[t * 2 + 1] = (float)(p1 / s);
    idx[t * 2 + 0] = i0;
    idx[t * 2 + 1] = i1;
  }
}

// LDS-aggregated expert histogram: 64 blocks -> 8 global atomics each
__global__ __launch_bounds__(256) void hist_k(const int* __restrict__ idx,
                                              int* __restrict__ cnt) {
  __shared__ int h[EE];
  if (threadIdx.x < EE) h[threadIdx.x] = 0;
  __syncthreads();
  int i = blockIdx.x * 256 + threadIdx.x;          // gridDim.x*256 == TT
  atomicAdd(&h[idx[i * 2 + 0]], 1);
  atomicAdd(&h[idx[i * 2 + 1]], 1);
  __syncthreads();
  if (threadIdx.x < EE) atomicAdd(&cnt[threadIdx.x], h[threadIdx.x]);
}

__global__ void prefix_k(const int* __restrict__ cnt, int* __restrict__ eoff,
                         int* __restrict__ cur) {
  if (threadIdx.x == 0) {
    int s = 0;
    for (int e = 0; e < EE; e++) { eoff[e] = s; cur[e] = s; s += cnt[e]; }
    eoff[EE] = s;   // == 2*TT
  }
}

__global__ __launch_bounds__(256) void scatter_k(const int* __restrict__ idx,
                                                 int* __restrict__ cur,
                                                 int* __restrict__ rowsb) {
  int t = blockIdx.x * 256 + threadIdx.x;
  int lane = threadIdx.x & 63;
  unsigned long long lt = (lane == 63) ? 0x7fffffffffffffffull
                                       : ((1ull << lane) - 1ull);
  #pragma unroll
  for (int k = 0; k < 2; k++) {
    int e = idx[t * 2 + k];
    int pos = 0;
    #pragma unroll
    for (int ex = 0; ex < EE; ex++) {
      unsigned long long m = __ballot(e == ex);
      if (e == ex) {
        int leader = __ffsll((unsigned long long)m) - 1;
        int base = 0;
        if (lane == leader) base = atomicAdd(&cur[ex], __popcll(m));
        base = __shfl(base, leader, 64);
        pos = base + __popcll(m & lt);
      }
    }
    rowsb[pos] = t * 2 + k;
  }
}

// ---------------- routed GEMM: 128x128 tile, BK=32, double-buffered LDS, ----
// ---------------- LDS-staged coalesced epilogue                         ----
// MODE 0: A = xbf gathered via rowsb, Out = hbuf[(r-w0)] = relu(A@W1t^T + b1)
// MODE 1: A = hbuf[(r-w0)],           Out[slot]          = A@W2t^T + b2
#define CSTRIDE 136   // u16; 272B rows: 16B-aligned granules, banks stagger by 4/row
template <int MODE>
__global__ __launch_bounds__(256) void ffn_gemm(const ushort* __restrict__ A,
                                                const ushort* __restrict__ Bt,
                                                const float* __restrict__ bias,
                                                ushort* __restrict__ Out,
                                                const int* __restrict__ rowsb,
                                                const int* __restrict__ eoff,
                                                int K, int N, int w0, int w1) {
  const int e = blockIdx.z;
  const int n0 = blockIdx.x * 128;
  const int e0 = eoff[e];
  const int rows_e = eoff[e + 1] - e0;
  const int j0 = (e0 >= w0) ? 0 : ((w0 - e0 + 127) >> 7);
  const int m0 = (j0 + blockIdx.y) << 7;
  const int fr = e0 + m0;                    // first routed row of this tile
  if (m0 >= rows_e || fr >= w1) return;

  // [0,4096)=A0 [4096,8192)=B0 [8192,12288)=A1 [12288,16384)=B1 (u16 idx);
  // epilogue reuses the whole array as C[128][CSTRIDE]
  __shared__ __align__(16) ushort smem[128 * CSTRIDE];

  const int tid = threadIdx.x;
  const int wave = tid >> 6, lane = tid & 63;
  const int ln15 = lane & 15, kq = lane >> 4;
  const int wr = wave >> 1, wc = wave & 1;

  // staging geometry: LDS byte o = row*64 + kbyte; dest is wave-uniform,
  // HW adds lane*16B. Each wave fills rows [wave*32, wave*32+32).
  const int o0 = wave * 2048 + lane * 16;
  const int o1 = o0 + 1024;
  const int rA0 = o0 >> 6, kc0 = (o0 >> 4) & 3;
  const int rA1 = o1 >> 6, kc1 = (o1 >> 4) & 3;

  size_t aoff0, aoff1;
  {
    const int r0 = min(fr + rA0, 2 * TT - 1);
    const int r1 = min(fr + rA1, 2 * TT - 1);
    if (MODE == 0) {
      aoff0 = (size_t)(rowsb[r0] >> 1) * K + kc0 * 8;
      aoff1 = (size_t)(rowsb[r1] >> 1) * K + kc1 * 8;
    } else {
      aoff0 = (size_t)(r0 - w0) * K + kc0 * 8;
      aoff1 = (size_t)(r1 - w0) * K + kc1 * 8;
    }
  }
  const size_t boff0 = ((size_t)e * N + n0 + rA0) * K + kc0 * 8;
  const size_t boff1 = ((size_t)e * N + n0 + rA1) * K + kc1 * 8;

  auto stage = [&](int bs, int k0) {
    ushort* Ab = smem + bs * 8192;
    ushort* Bb = Ab + 4096;
    g2l16(A + aoff0 + k0, Ab + wave * 1024);
    g2l16(A + aoff1 + k0, Ab + wave * 1024 + 512);
    g2l16(Bt + boff0 + k0, Bb + wave * 1024);
    g2l16(Bt + boff1 + k0, Bb + wave * 1024 + 512);
  };

  f32x4 acc[4][4];
  #pragma unroll
  for (int m = 0; m < 4; m++)
    #pragma unroll
    for (int n = 0; n < 4; n++) acc[m][n] = (f32x4){0.f, 0.f, 0.f, 0.f};

  const int nt = K >> 5;
  stage(0, 0);
  __syncthreads();                           // drains vmcnt(0): tile 0 ready

  for (int t = 0; t < nt; ++t) {
    const int cur = t & 1;
    if (t + 1 < nt) stage(cur ^ 1, (t + 1) << 5);   // prefetch next tile

    const ushort* As = smem + cur * 8192;
    const ushort* Bs = As + 4096;
    bf16x8 a[4], b[4];
    #pragma unroll
    for (int m = 0; m < 4; m++)
      a[m] = *(const bf16x8*)(As + (wr * 64 + m * 16 + ln15) * 32 + kq * 8);
    #pragma unroll
    for (int n = 0; n < 4; n++)
      b[n] = *(const bf16x8*)(Bs + (wc * 64 + n * 16 + ln15) * 32 + kq * 8);
    __builtin_amdgcn_s_setprio(1);
    #pragma unroll
    for (int m = 0; m < 4; m++)
      #pragma unroll
      for (int n = 0; n < 4; n++)
        acc[m][n] = __builtin_amdgcn_mfma_f32_16x16x32_bf16(a[m], b[n], acc[m][n], 0, 0, 0);
    __builtin_amdgcn_s_setprio(0);
    // one barrier per K-step: its vmcnt(0) drain completes the prefetch and
    // all waves' lgkmcnt hit 0 before their MFMAs -> buffer swap is safe
    __syncthreads();
  }

  // ---- epilogue: acc -> LDS C-tile (bf16), then coalesced 16B stores ----
  // C/D fragment: col = ln15, row = kq*4 + j (m89-verified layout)
  #pragma unroll
  for (int n = 0; n < 4; n++) {
    const int col = wc * 64 + n * 16 + ln15;
    const float bv = bias[(size_t)e * N + n0 + col];
    #pragma unroll
    for (int m = 0; m < 4; m++) {
      #pragma unroll
      for (int j = 0; j < 4; j++) {
        const int row = wr * 64 + m * 16 + kq * 4 + j;
        float v = acc[m][n][j] + bv;
        if (MODE == 0) v = fmaxf(v, 0.0f);
        smem[row * CSTRIDE + col] = f2bf(v);
      }
    }
  }
  __syncthreads();

  // writeback: pass p covers rows [p*16, p*16+16); 16 lanes/row x 16B = 256B
  const int gr = tid & 15;          // granule (16B unit) within row
  const int rr = tid >> 4;          // row within pass
  const int rows_left = rows_e - m0;
  #pragma unroll
  for (int p = 0; p < 8; p++) {
    const int r = p * 16 + rr;
    if (r < rows_left) {
      const uint4 v = *(const uint4*)(smem + r * CSTRIDE + gr * 8);
      const int rg = fr + r;
      if (MODE == 0) {
        *(uint4*)(Out + (size_t)(rg - w0) * N + n0 + gr * 8) = v;
      } else {
        const int slot = rowsb[rg];            // token*2 + k
        *(uint4*)(Out + (size_t)slot * N + n0 + gr * 8) = v;
      }
    }
  }
}

// ---------------- in-place combine (d_out: bf16 slot rows -> fp32 rows) ----
__global__ __launch_bounds__(256) void combine_k(float* __restrict__ out,
                                                 const float* __restrict__ wk) {
  const int t = blockIdx.x;
  const int dq = threadIdx.x;
  const ushort4* u4 = (const ushort4*)out;
  ushort4 a = u4[(size_t)t * 512 + dq];
  ushort4 b = u4[(size_t)t * 512 + 256 + dq];
  float w0 = wk[t * 2], w1 = wk[t * 2 + 1];
  float4 r;
  r.x = w0 * bf2f(a.x) + w1 * bf2f(b.x);
  r.y = w0 * bf2f(a.y) + w1 * bf2f(b.y);
  r.z = w0 * bf2f(a.z) + w1 * bf2f(b.z);
  r.w = w0 * bf2f(a.w) + w1 * bf2f(b.w);
  __syncthreads();   // all block reads complete before any write
  ((float4*)out)[(size_t)t * 256 + dq] = r;
}

// ---------------- launch ----------------
extern "C" void kernel_launch(void* const* d_in, const int* in_sizes, int n_in,
                              void* d_out, int out_size, void* d_ws, size_t ws_size,
                              hipStream_t stream) {
  const float* x  = (const float*)d_in[0];
  const float* Wg = (const float*)d_in[1];
  const float* bg = (const float*)d_in[2];
  const float* W1 = (const float*)d_in[3];
  const float* b1 = (const float*)d_in[4];
  const float* W2 = (const float*)d_in[5];
  const float* b2 = (const float*)d_in[6];

  // ---- workspace carve-up: control first, then bf16 buffers, then hbuf ----
  char* ws = (char*)d_ws;
  float* wk    = (float*)ws;                  // 2*TT
  int*   idx   = (int*)(wk + 2 * TT);         // 2*TT
  int*   rowsb = idx + 2 * TT;                // 2*TT
  int*   cnt   = rowsb + 2 * TT;              // EE
  int*   eoff  = cnt + EE;                    // EE+1
  int*   cur   = eoff + EE + 1;               // EE
  size_t ctl_end = (((size_t)((char*)(cur + EE) - ws)) + 255) & ~(size_t)255;
  ushort* xbf = (ushort*)(ws + ctl_end);      // TT*DD        (32 MiB)
  ushort* w1t = xbf + (size_t)TT * DD;        // EE*HH*DD     (32 MiB)
  ushort* w2t = w1t + (size_t)EE * HH * DD;   // EE*DD*HH     (32 MiB)
  char*   hb  = (char*)(w2t + (size_t)EE * DD * HH);
  const size_t fixed = (size_t)(hb - ws);

  // adaptive hbuf window size (rows, multiple of 128, +128 straddle slack)
  long long rows_avail = (ws_size > fixed)
      ? (long long)((ws_size - fixed) / ((size_t)HH * 2)) : 0;
  int usable;
  if (rows_avail >= 2 * TT) usable = 2 * TT;
  else usable = (int)(((rows_avail - 128) / 128) * 128);

  if (usable < 1024) {
    float val = 100.0f + (float)(ws_size >> 20);
    diag_k<<<TT * DD / 256, 256, 0, stream>>>((float*)d_out, val);
    return;
  }
  ushort* hbuf  = (ushort*)hb;
  ushort* yslot = (ushort*)d_out;   // 2*TT x DD bf16 == TT x DD fp32 bytes

  hipMemsetAsync(cnt, 0, EE * sizeof(int), stream);

  cvt_x_k<<<TT * DD / 4 / 256, 256, 0, stream>>>((const float4*)x, (ushort4*)xbf);
  // W1 [E][D][H] -> w1t [E][H][D]
  cvt_t_k<<<dim3(HH / 32, DD / 32, EE), dim3(32, 8), 0, stream>>>(W1, w1t, DD, HH);
  // W2 [E][H][D] -> w2t [E][D][H]
  cvt_t_k<<<dim3(DD / 32, HH / 32, EE), dim3(32, 8), 0, stream>>>(W2, w2t, HH, DD);

  gate_k<<<TT / 4, 256, 0, stream>>>(x, Wg, bg, wk, idx);
  hist_k<<<TT / 256, 256, 0, stream>>>(idx, cnt);
  prefix_k<<<1, 64, 0, stream>>>(cnt, eoff, cur);
  scatter_k<<<TT / 256, 256, 0, stream>>>(idx, cur, rowsb);

  int maxtiles = usable / 128 + 1;
  if (maxtiles > 2 * TT / 128) maxtiles = 2 * TT / 128;
  for (int win0 = 0; win0 < 2 * TT; win0 += usable) {
    int win1 = min(win0 + usable, 2 * TT);
    ffn_gemm<0><<<dim3(HH / 128, maxtiles, EE), 256, 0, stream>>>(
        xbf, w1t, b1, hbuf, rowsb, eoff, DD, HH, win0, win1);
    ffn_gemm<1><<<dim3(DD / 128, maxtiles, EE), 256, 0, stream>>>(
        hbuf, w2t, b2, yslot, rowsb, eoff, HH, DD, win0, win1);
  }

  combine_k<<<TT, 256, 0, stream>>>((float*)d_out, wk);
}